// Round 3
// baseline (651.435 us; speedup 1.0000x reference)
//
#include <hip/hip_runtime.h>

typedef _Float16 f16;
typedef _Float16 f16x8 __attribute__((ext_vector_type(8)));
typedef _Float16 f16x4 __attribute__((ext_vector_type(4)));
typedef float    f32x4 __attribute__((ext_vector_type(4)));

#define N_TOK   100000
#define NPAD    100032         // 3126 * 32 = 1563 * 64
#define NT1     1563           // k1 tiles (64 rows)
#define CDIM    512
#define KSTEPS  (NPAD/32)      // 3126
#define K2SPL   128            // split-K slots

// ---------------- workspace layout (bytes) ----------------
#define O_WT     ((size_t)0)                       // w^T fp16 [512][NPAD]
#define SZ_WT    ((size_t)512*NPAD*2)
#define O_YT     (O_WT + SZ_WT)                    // y^T fp16 [64][NPAD]
#define SZ_YT    ((size_t)64*NPAD*2)
#define O_WFR    (O_YT + SZ_YT)                    // frag-linear W+w1 fp16
#define SZ_WFR   ((size_t)16*4*9*64*8*2)
#define O_SPP    (O_WFR + SZ_WFR)                  // s_pre partials [128][32768] f32
#define SZ_SPP   ((size_t)K2SPL*32768*4)
#define O_DPP    (O_SPP + SZ_SPP)                  // d partials [128][512] f32
#define SZ_DPP   ((size_t)K2SPL*512*4)
#define O_SPRE   (O_DPP + SZ_DPP)                  // s_pre [512][64] f32
#define SZ_SPRE  ((size_t)32768*4)
#define O_DSTD   (O_SPRE + SZ_SPRE)                // d [512] f32
#define SZ_DSTD  ((size_t)512*4)
#define O_SOUT   (O_DSTD + SZ_DSTD)                // s_out^T fp16 [8][64dh][64m]
#define SZ_SOUT  ((size_t)8*64*64*2)
#define O_WN     (O_SOUT + SZ_SOUT)                // w fp16 [NPAD][512]  (m-fast, for K4)
#define SZ_WN    ((size_t)NPAD*512*2)

// ---------------- K0: pack W = [w_slice; w1] (576x512) into MFMA-fragment-linear fp16 ----------------
__global__ void k0_pack(const float* __restrict__ wsf, const float* __restrict__ w1f,
                        f16* __restrict__ wfr) {
    int c = blockIdx.x * 256 + threadIdx.x;      // 36864 chunks total
    int lane = c & 63, g = c >> 6;               // g in 0..575
    int u  = g % 9,  r = g / 9;                  // r in 0..63
    int we = r & 3,  kg = r >> 2;
    int col = lane & 15, quad = lane >> 4;
    int k = kg * 32 + quad * 8;
    const float* src;
    if (u < 8) src = wsf + (size_t)(we*128 + u*16 + col) * CDIM + k;
    else       src = w1f + (size_t)(we*16  + col) * CDIM + k;
    float4 a = *(const float4*)(src);
    float4 b = *(const float4*)(src + 4);
    f16x8 h;
    h[0]=(f16)a.x; h[1]=(f16)a.y; h[2]=(f16)a.z; h[3]=(f16)a.w;
    h[4]=(f16)b.x; h[5]=(f16)b.y; h[6]=(f16)b.z; h[7]=(f16)b.w;
    *(f16x8*)(wfr + (size_t)c * 8) = h;
}

// ---------------- K1: slice GEMM + softmax + y GEMM + dual-layout w emit ----------------
// block = 256 threads (4 waves), one 64-row n-tile per block.
// Full X tile (64 x 512) staged to LDS ONCE -> K-loop has ZERO barriers / LDS writes,
// so the compiler can pipeline the 9 wfr loads per step across steps (no vmcnt(0) drains).
#define XPITCH 520                               // f16; row = 1040 B, 16B-aligned
#define TPITCH 72                                // wT stage pitch (f16)
#define NPITCH 536                               // wN stage pitch (f16)
__launch_bounds__(256, 2)
__global__ void k1_slice(const float* __restrict__ x, const float* __restrict__ temperature,
                         const f16* __restrict__ wfr, const float* __restrict__ bsl,
                         f16* __restrict__ wT, f16* __restrict__ yT, f16* __restrict__ wN) {
    __shared__ f16 smem[512 * TPITCH];           // 73728 B, aliased 3 ways
    f16* lX = smem;                               // [64][XPITCH] = 66560 B
    f16* lT = smem;                               // [512][TPITCH] wT stage
    f16* lN = smem;                               // [64][NPITCH] wN stage

    const int tid  = threadIdx.x;
    const int wave = tid >> 6;
    const int lane = tid & 63;
    const int quad = lane >> 4;
    const int col  = lane & 15;
    const int n0   = blockIdx.x * 64;

    // ---- stage the full 64x512 x tile (fp32 -> fp16), one barrier total ----
    const int srow = tid >> 2, sch = tid & 3;
    int snr = n0 + srow; if (snr > N_TOK - 1) snr = N_TOK - 1;
    const float* sbase = x + (size_t)snr * CDIM + sch * 8;
    #pragma unroll
    for (int kg = 0; kg < 16; ++kg) {
        float4 a = *(const float4*)(sbase + kg * 32);
        float4 b = *(const float4*)(sbase + kg * 32 + 4);
        f16x8 h;
        h[0]=(f16)a.x; h[1]=(f16)a.y; h[2]=(f16)a.z; h[3]=(f16)a.w;
        h[4]=(f16)b.x; h[5]=(f16)b.y; h[6]=(f16)b.z; h[7]=(f16)b.w;
        *(f16x8*)(&lX[srow * XPITCH + kg * 32 + sch * 8]) = h;
    }

    f32x4 acc[4][9];
    #pragma unroll
    for (int nf = 0; nf < 4; ++nf)
        #pragma unroll
        for (int u = 0; u < 9; ++u) acc[nf][u] = f32x4{0.f,0.f,0.f,0.f};

    __syncthreads();

    // ---- barrier-free K-loop: 16 steps x 36 MFMA ----
    #pragma unroll 2
    for (int kg = 0; kg < 16; ++kg) {
        const f16* wb = wfr + ((size_t)(kg*4 + wave) * 9) * 512 + (size_t)lane * 8;
        f16x8 bf[9];
        #pragma unroll
        for (int u = 0; u < 9; ++u) bf[u] = *(const f16x8*)(wb + u * 512);

        f16x8 af[4];
        #pragma unroll
        for (int nf = 0; nf < 4; ++nf)
            af[nf] = *(const f16x8*)(&lX[(nf*16 + col) * XPITCH + kg * 32 + quad * 8]);

        #pragma unroll
        for (int nf = 0; nf < 4; ++nf)
            #pragma unroll
            for (int u = 0; u < 9; ++u)
                acc[nf][u] = __builtin_amdgcn_mfma_f32_16x16x32_f16(af[nf], bf[u], acc[nf][u], 0, 0, 0);
    }

    // ---- bias + temperature ----
    #pragma unroll
    for (int u = 0; u < 8; ++u) {
        float b = bsl[wave*128 + u*16 + col];
        #pragma unroll
        for (int nf = 0; nf < 4; ++nf)
            #pragma unroll
            for (int r = 0; r < 4; ++r) acc[nf][u][r] += b;
    }
    float invt[2];
    #pragma unroll
    for (int hh = 0; hh < 2; ++hh) {
        float tv = temperature[wave*2 + hh];
        tv = fminf(fmaxf(tv, 0.1f), 5.0f);
        invt[hh] = 1.0f / tv;
    }

    __syncthreads();   // all waves done reading lX; lT may overwrite

    // ---- softmax over M=64 per head; normalized w kept in acc; wT staged to LDS ----
    #pragma unroll
    for (int nf = 0; nf < 4; ++nf) {
        const int nloc = nf*16 + quad*4;
        #pragma unroll
        for (int hh = 0; hh < 2; ++hh) {
            float mx[4];
            #pragma unroll
            for (int r = 0; r < 4; ++r) {
                float m01 = fmaxf(acc[nf][hh*4+0][r], acc[nf][hh*4+1][r]);
                float m23 = fmaxf(acc[nf][hh*4+2][r], acc[nf][hh*4+3][r]);
                mx[r] = fmaxf(m01, m23);
            }
            #pragma unroll
            for (int d = 1; d < 16; d <<= 1)
                #pragma unroll
                for (int r = 0; r < 4; ++r) mx[r] = fmaxf(mx[r], __shfl_xor(mx[r], d));
            float sm[4] = {0.f, 0.f, 0.f, 0.f};
            #pragma unroll
            for (int uu = 0; uu < 4; ++uu)
                #pragma unroll
                for (int r = 0; r < 4; ++r) {
                    float ev = __expf((acc[nf][hh*4+uu][r] - mx[r]) * invt[hh]);
                    acc[nf][hh*4+uu][r] = ev;
                    sm[r] += ev;
                }
            #pragma unroll
            for (int d = 1; d < 16; d <<= 1)
                #pragma unroll
                for (int r = 0; r < 4; ++r) sm[r] += __shfl_xor(sm[r], d);
            #pragma unroll
            for (int r = 0; r < 4; ++r) sm[r] = 1.0f / sm[r];
            #pragma unroll
            for (int uu = 0; uu < 4; ++uu) {
                f16x4 pk;
                #pragma unroll
                for (int r = 0; r < 4; ++r) {
                    acc[nf][hh*4+uu][r] *= sm[r];            // keep normalized w in acc
                    int n = n0 + nloc + r;
                    pk[r] = (n < N_TOK) ? (f16)acc[nf][hh*4+uu][r] : (f16)0.f;
                }
                int e = wave*128 + (hh*4 + uu)*16 + col;
                *(f16x4*)(lT + (size_t)e*TPITCH + nloc) = pk;
            }
        }
        // y columns (frag u==8): straight to yT
        {
            f16x4 pk;
            #pragma unroll
            for (int r = 0; r < 4; ++r) {
                int n = n0 + nloc + r;
                pk[r] = (n < N_TOK) ? (f16)acc[nf][8][r] : (f16)0.f;
            }
            *(f16x4*)(yT + (size_t)(wave*16 + col) * NPAD + n0 + nloc) = pk;
        }
    }
    __syncthreads();

    // ---- coalesced wT store: 512 e-rows x 64 n ----
    #pragma unroll
    for (int i = 0; i < 16; ++i) {
        int id = tid + i*256;                 // 4096 = 512 rows x 8 chunks(8 f16)
        int e = id >> 3, p = id & 7;
        f16x8 v = *(const f16x8*)(lT + (size_t)e*TPITCH + p*8);
        *(f16x8*)(wT + (size_t)e*NPAD + n0 + p*8) = v;
    }

    // ---- optional wN [n][e] emit (m-fast layout for K4) ----
    if (wN != nullptr) {
        __syncthreads();                      // lT reads done; reuse LDS as lN
        #pragma unroll
        for (int nf = 0; nf < 4; ++nf) {
            const int nloc = nf*16 + quad*4;
            #pragma unroll
            for (int hh = 0; hh < 2; ++hh)
                #pragma unroll
                for (int uu = 0; uu < 4; ++uu) {
                    int e = wave*128 + (hh*4 + uu)*16 + col;
                    #pragma unroll
                    for (int r = 0; r < 4; ++r)
                        lN[(size_t)(nloc + r)*NPITCH + e] = (f16)acc[nf][hh*4+uu][r];
                }
        }
        __syncthreads();
        #pragma unroll
        for (int i = 0; i < 16; ++i) {
            int id = tid + i*256;             // 4096 = 64 n-rows x 64 chunks(8 f16)
            int n = id >> 6, ec = id & 63;
            f16x8 v = *(const f16x8*)(lN + (size_t)n*NPITCH + ec*8);
            *(f16x8*)(wN + (size_t)(n0 + n)*512 + ec*8) = v;
        }
    }
}

// ---------------- K2: s_pre = sum_n w[n,e]*y[n,d]  (contiguous split-K x e-quarter) ----------------
// grid = 512: bid = slot*4 + equad; each block: 128e x 64d over a CONTIGUOUS ~24-step
// k-chunk (streaming reads, full L2 lines), with an explicit 2-stage A/B load pipeline.
#define K2_LOAD(AF, BF, kss)                                                         \
    {   int nb_ = (kss)*32 + quad*8;                                                 \
        _Pragma("unroll")                                                            \
        for (int v = 0; v < 4; ++v)                                                  \
            BF[v] = *(const f16x8*)(yT + (size_t)(v*16 + col)*NPAD + nb_);           \
        _Pragma("unroll")                                                            \
        for (int u = 0; u < 2; ++u)                                                  \
            AF[u] = *(const f16x8*)(wT + (size_t)(ebase + u*16 + col)*NPAD + nb_);   \
    }
#define K2_MFMA(AF, BF)                                                              \
    {   _Pragma("unroll")                                                            \
        for (int u = 0; u < 2; ++u) {                                                \
            _Pragma("unroll")                                                        \
            for (int v = 0; v < 4; ++v)                                              \
                acc[u][v] = __builtin_amdgcn_mfma_f32_16x16x32_f16(AF[u], BF[v], acc[u][v], 0, 0, 0); \
            float s_ = 0.f;                                                          \
            _Pragma("unroll")                                                        \
            for (int j = 0; j < 8; ++j) s_ += (float)AF[u][j];                       \
            dac[u] += s_;                                                            \
        }                                                                            \
    }
__launch_bounds__(256, 4)
__global__ void k2_spre(const f16* __restrict__ wT, const f16* __restrict__ yT,
                        float* __restrict__ spp, float* __restrict__ dpp) {
    const int tid = threadIdx.x, wave = tid >> 6, lane = tid & 63;
    const int quad = lane >> 4, col = lane & 15;
    const int slot = blockIdx.x >> 2, equad = blockIdx.x & 3;
    const int ebase = equad * 128 + wave * 32;

    const int ks0 = (slot * KSTEPS) >> 7;
    const int ks1 = ((slot + 1) * KSTEPS) >> 7;

    f32x4 acc[2][4];
    float dac[2];
    #pragma unroll
    for (int u = 0; u < 2; ++u) {
        dac[u] = 0.f;
        #pragma unroll
        for (int v = 0; v < 4; ++v) acc[u][v] = f32x4{0.f,0.f,0.f,0.f};
    }

    f16x8 afA[2], bfA[4], afB[2], bfB[4];
    K2_LOAD(afA, bfA, ks0)
    int ks = ks0;
    for (; ks + 2 <= ks1; ks += 2) {
        K2_LOAD(afB, bfB, ks + 1)
        K2_MFMA(afA, bfA)
        K2_LOAD(afA, bfA, ks + 2)   // one-step overread at chunk end stays in workspace; unused
        K2_MFMA(afB, bfB)
    }
    if (ks < ks1) K2_MFMA(afA, bfA)

    #pragma unroll
    for (int u = 0; u < 2; ++u) {
        dac[u] += __shfl_xor(dac[u], 16);
        dac[u] += __shfl_xor(dac[u], 32);
    }
    if (quad == 0) {
        #pragma unroll
        for (int u = 0; u < 2; ++u)
            dpp[slot*512 + ebase + u*16 + col] = dac[u];
    }
    // partial layout: [slot][equad*8192 + ((wave*2+u)*4+v)*256 + lane*4]
    float* dst = spp + (size_t)slot * 32768 + (size_t)equad * 8192;
    #pragma unroll
    for (int u = 0; u < 2; ++u)
        #pragma unroll
        for (int v = 0; v < 4; ++v)
            *(f32x4*)(dst + (size_t)((wave*2 + u)*4 + v)*256 + (size_t)lane*4) = acc[u][v];
}

// ---------------- K2r: reduce partials, de-swizzle frag order ----------------
__global__ void k2r_reduce(const float* __restrict__ spp, const float* __restrict__ dpp,
                           float* __restrict__ spre, float* __restrict__ dstd) {
    int i = blockIdx.x*256 + threadIdx.x;   // 32768
    float s = 0.f;
    for (int p = 0; p < K2SPL; ++p) s += spp[(size_t)p*32768 + i];
    int r = i & 3, L = (i >> 2) & 63, v = (i >> 8) & 3, g = (i >> 10) & 7, eq = (i >> 13) & 3;
    int e = eq*128 + (g >> 1)*32 + (g & 1)*16 + (L >> 4)*4 + r;
    int d = v*16 + (L & 15);
    spre[e*64 + d] = s;
    if (i < 512) {
        float tt = 0.f;
        for (int p = 0; p < K2SPL; ++p) tt += dpp[p*512 + i];
        dstd[i] = tt;
    }
}

// ---------------- K3: per-head middle block (exact fp32, all-LDS, 256 threads) ----------------
__global__ void k3_attn(const float* __restrict__ spre, const float* __restrict__ dstd,
                        const float* __restrict__ b1, const float* __restrict__ wq,
                        const float* __restrict__ wk, const float* __restrict__ wv,
                        const float* __restrict__ w3, const float* __restrict__ b3,
                        f16* __restrict__ sout) {
    __shared__ float wa[64][65], wb[64][65], wc[64][65];   // wq,wk,wv; wa reused for w3
    __shared__ float ss[64][65], qq[64][65], kk[64][65], vv[64][65], sc[64][65];
    const int h = blockIdx.x, tid = threadIdx.x;

    for (int i = tid; i < 4096; i += 256) {
        int r = i >> 6, c = i & 63;
        wa[r][c] = wq[i];
        wb[r][c] = wk[i];
        wc[r][c] = wv[i];
        ss[r][c] = spre[h*4096 + i] / (dstd[h*64 + r] + 1e-5f) + b1[c];
    }
    __syncthreads();

    #pragma unroll
    for (int it = 0; it < 16; ++it) {
        int m = it*4 + (tid >> 6), e = tid & 63;
        float aq = 0.f, ak = 0.f, av = 0.f;
        #pragma unroll 8
        for (int d = 0; d < 64; ++d) {
            float sv = ss[m][d];
            aq += sv * wa[e][d];
            ak += sv * wb[e][d];
            av += sv * wc[e][d];
        }
        qq[m][e] = aq; kk[m][e] = ak; vv[m][e] = av;
    }
    __syncthreads();

    for (int i = tid; i < 4096; i += 256) wa[i >> 6][i & 63] = w3[i];
    #pragma unroll
    for (int it = 0; it < 16; ++it) {
        int m = it*4 + (tid >> 6), l = tid & 63;
        float a = 0.f;
        #pragma unroll 8
        for (int e = 0; e < 64; ++e) a += qq[m][e] * kk[l][e];
        sc[m][l] = a * 0.125f;
    }
    __syncthreads();

    if (tid < 64) {
        int m = tid;
        float mx = -1e30f;
        #pragma unroll 8
        for (int l = 0; l < 64; ++l) mx = fmaxf(mx, sc[m][l]);
        float sm = 0.f;
        #pragma unroll 8
        for (int l = 0; l < 64; ++l) { float ev = __expf(sc[m][l] - mx); sc[m][l] = ev; sm += ev; }
        float rs = 1.0f / sm;
        #pragma unroll 8
        for (int l = 0; l < 64; ++l) sc[m][l] *= rs;
    }
    __syncthreads();

    #pragma unroll
    for (int it = 0; it < 16; ++it) {
        int m = it*4 + (tid >> 6), e = tid & 63;
        float a = 0.f;
        #pragma unroll 8
        for (int l = 0; l < 64; ++l) a += sc[m][l] * vv[l][e];
        ss[m][e] = a;
    }
    __syncthreads();

    #pragma unroll
    for (int it = 0; it < 16; ++it) {
        int d = it*4 + (tid >> 6), m = tid & 63;
        float a = b3[d];
        #pragma unroll 8
        for (int e = 0; e < 64; ++e) a += ss[m][e] * wa[d][e];
        sout[(h*64 + d)*64 + m] = (f16)a;
    }
}

// ---------------- K4 (wN path): deslice, pure streaming, no LDS ----------------
__launch_bounds__(256, 4)
__global__ void k4_wn(const f16* __restrict__ wN, const f16* __restrict__ sout,
                      float* __restrict__ out) {
    const int tid = threadIdx.x, wave = tid >> 6, lane = tid & 63;
    const int quad = lane >> 4, col = lane & 15;
    const int n0 = blockIdx.x * 32;

    f32x4 acc[2][2][4];
    #pragma unroll
    for (int hh = 0; hh < 2; ++hh)
        #pragma unroll
        for (int t = 0; t < 2; ++t)
            #pragma unroll
            for (int v = 0; v < 4; ++v) acc[hh][t][v] = f32x4{0.f,0.f,0.f,0.f};

    #pragma unroll
    for (int hh = 0; hh < 2; ++hh) {
        int h = wave*2 + hh;
        #pragma unroll
        for (int ks = 0; ks < 2; ++ks) {
            f16x8 af[2], bf[4];
            #pragma unroll
            for (int t = 0; t < 2; ++t)
                af[t] = *(const f16x8*)(wN + (size_t)(n0 + t*16 + col)*512 + h*64 + ks*32 + quad*8);
            #pragma unroll
            for (int v = 0; v < 4; ++v)
                bf[v] = *(const f16x8*)(sout + (size_t)(h*64 + v*16 + col)*64 + ks*32 + quad*8);
            #pragma unroll
            for (int t = 0; t < 2; ++t)
                #pragma unroll
                for (int v = 0; v < 4; ++v)
                    acc[hh][t][v] = __builtin_amdgcn_mfma_f32_16x16x32_f16(af[t], bf[v], acc[hh][t][v], 0, 0, 0);
        }
    }

    #pragma unroll
    for (int hh = 0; hh < 2; ++hh) {
        int h = wave*2 + hh;
        #pragma unroll
        for (int t = 0; t < 2; ++t)
            #pragma unroll
            for (int v = 0; v < 4; ++v)
                #pragma unroll
                for (int r = 0; r < 4; ++r) {
                    int n = n0 + t*16 + quad*4 + r;
                    if (n < N_TOK)
                        out[(size_t)n*512 + h*64 + v*16 + col] = acc[hh][t][v][r];
                }
    }
}

// ---------------- K4 (fallback): original wT-gather version ----------------
__launch_bounds__(256, 2)
__global__ void k4_deslice(const f16* __restrict__ wT, const f16* __restrict__ sout,
                           float* __restrict__ out) {
    __shared__ f16 ldsW[512*68];
    const int tid = threadIdx.x, wave = tid >> 6, lane = tid & 63;
    const int quad = lane >> 4, col = lane & 15;
    const int n0 = blockIdx.x * 64;

    #pragma unroll
    for (int i = 0; i < 32; ++i) {
        int id = tid + i*256;
        int e = id >> 4, p = id & 15;
        f16x4 v = *(const f16x4*)(wT + (size_t)e*NPAD + n0 + p*4);
        *(f16x4*)(ldsW + (size_t)e*68 + p*4) = v;
    }
    __syncthreads();

    f32x4 acc[2][4][4];
    #pragma unroll
    for (int hh = 0; hh < 2; ++hh)
        #pragma unroll
        for (int t = 0; t < 4; ++t)
            #pragma unroll
            for (int v = 0; v < 4; ++v) acc[hh][t][v] = f32x4{0.f,0.f,0.f,0.f};

    #pragma unroll
    for (int hh = 0; hh < 2; ++hh) {
        int h = wave*2 + hh;
        #pragma unroll
        for (int ks = 0; ks < 2; ++ks) {
            f16x8 af[4];
            #pragma unroll
            for (int t = 0; t < 4; ++t) {
                f16x8 a;
                #pragma unroll
                for (int j = 0; j < 8; ++j)
                    a[j] = ldsW[(size_t)(h*64 + ks*32 + quad*8 + j)*68 + t*16 + col];
                af[t] = a;
            }
            #pragma unroll
            for (int v = 0; v < 4; ++v) {
                f16x8 bf = *(const f16x8*)(sout + (size_t)(h*64 + v*16 + col)*64 + ks*32 + quad*8);
                #pragma unroll
                for (int t = 0; t < 4; ++t)
                    acc[hh][t][v] = __builtin_amdgcn_mfma_f32_16x16x32_f16(af[t], bf, acc[hh][t][v], 0, 0, 0);
            }
        }
    }

    #pragma unroll
    for (int hh = 0; hh < 2; ++hh) {
        int h = wave*2 + hh;
        #pragma unroll
        for (int t = 0; t < 4; ++t)
            #pragma unroll
            for (int v = 0; v < 4; ++v)
                #pragma unroll
                for (int r = 0; r < 4; ++r) {
                    int n = n0 + t*16 + quad*4 + r;
                    if (n < N_TOK)
                        out[(size_t)n*512 + h*64 + v*16 + col] = acc[hh][t][v][r];
                }
    }
}

// ---------------- launcher ----------------
extern "C" void kernel_launch(void* const* d_in, const int* in_sizes, int n_in,
                              void* d_out, int out_size, void* d_ws, size_t ws_size,
                              hipStream_t stream) {
    const float* x           = (const float*)d_in[0];
    const float* temperature = (const float*)d_in[1];
    const float* w_slice     = (const float*)d_in[2];
    const float* b_slice     = (const float*)d_in[3];
    const float* w1          = (const float*)d_in[4];
    const float* b1          = (const float*)d_in[5];
    const float* wq          = (const float*)d_in[6];
    const float* wk          = (const float*)d_in[7];
    const float* wv          = (const float*)d_in[8];
    const float* w3          = (const float*)d_in[9];
    const float* b3          = (const float*)d_in[10];
    float* out = (float*)d_out;
    char*  ws  = (char*)d_ws;

    f16*   wT    = (f16*)(ws + O_WT);
    f16*   yT    = (f16*)(ws + O_YT);
    f16*   wfr   = (f16*)(ws + O_WFR);
    float* spp   = (float*)(ws + O_SPP);
    float* dpp   = (float*)(ws + O_DPP);
    float* spre  = (float*)(ws + O_SPRE);
    float* dstd  = (float*)(ws + O_DSTD);
    f16*   sout  = (f16*)(ws + O_SOUT);

    const int use_wn = (ws_size >= (O_WN + SZ_WN)) ? 1 : 0;
    f16* wN = use_wn ? (f16*)(ws + O_WN) : nullptr;

    k0_pack<<<144, 256, 0, stream>>>(w_slice, w1, wfr);
    k1_slice<<<NT1, 256, 0, stream>>>(x, temperature, wfr, b_slice, wT, yT, wN);
    k2_spre<<<K2SPL*4, 256, 0, stream>>>(wT, yT, spp, dpp);
    k2r_reduce<<<128, 256, 0, stream>>>(spp, dpp, spre, dstd);
    k3_attn<<<8, 256, 0, stream>>>(spre, dstd, b1, wq, wk, wv, w3, b3, sout);
    if (use_wn) k4_wn<<<KSTEPS, 256, 0, stream>>>(wN, sout, out);
    else        k4_deslice<<<NT1, 256, 0, stream>>>(wT, sout, out);
}

// Round 4
// 598.708 us; speedup vs baseline: 1.0881x; 1.0881x over previous
//
#include <hip/hip_runtime.h>

typedef _Float16 f16;
typedef _Float16 f16x8 __attribute__((ext_vector_type(8)));
typedef _Float16 f16x4 __attribute__((ext_vector_type(4)));
typedef float    f32x4 __attribute__((ext_vector_type(4)));

#define N_TOK   100000
#define NPAD    100032         // 3126 * 32 = 1563 * 64
#define NT1     1563           // k1 tiles (64 rows)
#define CDIM    512
#define KSTEPS  (NPAD/32)      // 3126
#define K2SPL   128            // split-K slots

// ---------------- workspace layout (bytes) ----------------
#define O_WT     ((size_t)0)                       // w^T fp16 [512][NPAD]
#define SZ_WT    ((size_t)512*NPAD*2)
#define O_YT     (O_WT + SZ_WT)                    // y^T fp16 [64][NPAD]
#define SZ_YT    ((size_t)64*NPAD*2)
#define O_WFR    (O_YT + SZ_YT)                    // frag-linear W+w1 fp16
#define SZ_WFR   ((size_t)16*4*9*64*8*2)
#define O_SPP    (O_WFR + SZ_WFR)                  // s_pre partials [128][32768] f32
#define SZ_SPP   ((size_t)K2SPL*32768*4)
#define O_DPP    (O_SPP + SZ_SPP)                  // d partials [128][512] f32
#define SZ_DPP   ((size_t)K2SPL*512*4)
#define O_SPRE   (O_DPP + SZ_DPP)                  // s_pre [512][64] f32
#define SZ_SPRE  ((size_t)32768*4)
#define O_DSTD   (O_SPRE + SZ_SPRE)                // d [512] f32
#define SZ_DSTD  ((size_t)512*4)
#define O_SOUT   (O_DSTD + SZ_DSTD)                // s_out^T fp16 [8][64dh][64m]
#define SZ_SOUT  ((size_t)8*64*64*2)

// ---------------- K0: pack W = [w_slice; w1] (576x512) into MFMA-fragment-linear fp16 ----------------
__global__ void k0_pack(const float* __restrict__ wsf, const float* __restrict__ w1f,
                        f16* __restrict__ wfr) {
    int c = blockIdx.x * 256 + threadIdx.x;      // 36864 chunks total
    int lane = c & 63, g = c >> 6;               // g in 0..575
    int u  = g % 9,  r = g / 9;                  // r in 0..63
    int we = r & 3,  kg = r >> 2;
    int col = lane & 15, quad = lane >> 4;
    int k = kg * 32 + quad * 8;
    const float* src;
    if (u < 8) src = wsf + (size_t)(we*128 + u*16 + col) * CDIM + k;
    else       src = w1f + (size_t)(we*16  + col) * CDIM + k;
    float4 a = *(const float4*)(src);
    float4 b = *(const float4*)(src + 4);
    f16x8 h;
    h[0]=(f16)a.x; h[1]=(f16)a.y; h[2]=(f16)a.z; h[3]=(f16)a.w;
    h[4]=(f16)b.x; h[5]=(f16)b.y; h[6]=(f16)b.z; h[7]=(f16)b.w;
    *(f16x8*)(wfr + (size_t)c * 8) = h;
}

// ---------------- K1: slice GEMM + softmax + y GEMM (round-2 proven structure, no wN) ----------------
// block = 256 threads (4 waves), one 64-row n-tile per block.
// X tile (64n x 32k per k-step) double-buffered in LDS; W fragments streamed from
// frag-linear global (L2-resident). Epilogue: LDS-coalesced wT store only.
#define XROW 40
#define TPITCH 72                                // wT stage pitch (f16): 144 B, 16B-aligned
__launch_bounds__(256, 2)
__global__ void k1_slice(const float* __restrict__ x, const float* __restrict__ temperature,
                         const f16* __restrict__ wfr, const float* __restrict__ bsl,
                         f16* __restrict__ wT, f16* __restrict__ yT) {
    __shared__ f16 smem[512 * TPITCH];           // 73728 B, aliased 2 ways
    f16* lX = smem;                               // [2][64*XROW] main-loop x tiles
    f16* lT = smem;                               // [512][TPITCH] wT stage

    const int tid  = threadIdx.x;
    const int wave = tid >> 6;
    const int lane = tid & 63;
    const int quad = lane >> 4;
    const int col  = lane & 15;
    const int n0   = blockIdx.x * 64;

    const int srow = tid >> 2, sch = tid & 3;
    int snr = n0 + srow; if (snr > N_TOK - 1) snr = N_TOK - 1;
    const float* sbase = x + (size_t)snr * CDIM + sch * 8;

    {
        float4 a = *(const float4*)(sbase);
        float4 b = *(const float4*)(sbase + 4);
        f16x8 h;
        h[0]=(f16)a.x; h[1]=(f16)a.y; h[2]=(f16)a.z; h[3]=(f16)a.w;
        h[4]=(f16)b.x; h[5]=(f16)b.y; h[6]=(f16)b.z; h[7]=(f16)b.w;
        *(f16x8*)(&lX[srow * XROW + sch * 8]) = h;
    }

    f32x4 acc[4][9];
    #pragma unroll
    for (int nf = 0; nf < 4; ++nf)
        #pragma unroll
        for (int u = 0; u < 9; ++u) acc[nf][u] = f32x4{0.f,0.f,0.f,0.f};

    __syncthreads();

    #pragma unroll 2
    for (int kg = 0; kg < 16; ++kg) {
        const f16* wb = wfr + ((size_t)(kg*4 + wave) * 9) * 512 + (size_t)lane * 8;
        f16x8 bf[9];
        #pragma unroll
        for (int u = 0; u < 9; ++u) bf[u] = *(const f16x8*)(wb + u * 512);

        float4 xa, xb;
        if (kg < 15) {
            xa = *(const float4*)(sbase + (kg + 1) * 32);
            xb = *(const float4*)(sbase + (kg + 1) * 32 + 4);
        }

        const f16* xbuf = lX + (kg & 1) * (64 * XROW);
        f16x8 af[4];
        #pragma unroll
        for (int nf = 0; nf < 4; ++nf)
            af[nf] = *(const f16x8*)(xbuf + (nf*16 + col) * XROW + quad * 8);

        #pragma unroll
        for (int nf = 0; nf < 4; ++nf)
            #pragma unroll
            for (int u = 0; u < 9; ++u)
                acc[nf][u] = __builtin_amdgcn_mfma_f32_16x16x32_f16(af[nf], bf[u], acc[nf][u], 0, 0, 0);

        if (kg < 15) {
            f16x8 h;
            h[0]=(f16)xa.x; h[1]=(f16)xa.y; h[2]=(f16)xa.z; h[3]=(f16)xa.w;
            h[4]=(f16)xb.x; h[5]=(f16)xb.y; h[6]=(f16)xb.z; h[7]=(f16)xb.w;
            *(f16x8*)(&lX[((kg + 1) & 1) * (64 * XROW) + srow * XROW + sch * 8]) = h;
        }
        __syncthreads();
    }

    // ---- bias + temperature ----
    #pragma unroll
    for (int u = 0; u < 8; ++u) {
        float b = bsl[wave*128 + u*16 + col];
        #pragma unroll
        for (int nf = 0; nf < 4; ++nf)
            #pragma unroll
            for (int r = 0; r < 4; ++r) acc[nf][u][r] += b;
    }
    float invt[2];
    #pragma unroll
    for (int hh = 0; hh < 2; ++hh) {
        float tv = temperature[wave*2 + hh];
        tv = fminf(fmaxf(tv, 0.1f), 5.0f);
        invt[hh] = 1.0f / tv;
    }

    // ---- softmax over M=64 per head; wT staged to LDS ----
    #pragma unroll
    for (int nf = 0; nf < 4; ++nf) {
        const int nloc = nf*16 + quad*4;
        #pragma unroll
        for (int hh = 0; hh < 2; ++hh) {
            float mx[4];
            #pragma unroll
            for (int r = 0; r < 4; ++r) {
                float m01 = fmaxf(acc[nf][hh*4+0][r], acc[nf][hh*4+1][r]);
                float m23 = fmaxf(acc[nf][hh*4+2][r], acc[nf][hh*4+3][r]);
                mx[r] = fmaxf(m01, m23);
            }
            #pragma unroll
            for (int d = 1; d < 16; d <<= 1)
                #pragma unroll
                for (int r = 0; r < 4; ++r) mx[r] = fmaxf(mx[r], __shfl_xor(mx[r], d));
            float sm[4] = {0.f, 0.f, 0.f, 0.f};
            #pragma unroll
            for (int uu = 0; uu < 4; ++uu)
                #pragma unroll
                for (int r = 0; r < 4; ++r) {
                    float ev = __expf((acc[nf][hh*4+uu][r] - mx[r]) * invt[hh]);
                    acc[nf][hh*4+uu][r] = ev;
                    sm[r] += ev;
                }
            #pragma unroll
            for (int d = 1; d < 16; d <<= 1)
                #pragma unroll
                for (int r = 0; r < 4; ++r) sm[r] += __shfl_xor(sm[r], d);
            #pragma unroll
            for (int r = 0; r < 4; ++r) sm[r] = 1.0f / sm[r];
            #pragma unroll
            for (int uu = 0; uu < 4; ++uu) {
                f16x4 pk;
                #pragma unroll
                for (int r = 0; r < 4; ++r) {
                    int n = n0 + nloc + r;
                    float wv = (n < N_TOK) ? acc[nf][hh*4+uu][r] * sm[r] : 0.0f;
                    pk[r] = (f16)wv;
                }
                int e = wave*128 + (hh*4 + uu)*16 + col;
                *(f16x4*)(lT + (size_t)e*TPITCH + nloc) = pk;
            }
        }
        // y columns (frag u==8): straight to yT
        {
            f16x4 pk;
            #pragma unroll
            for (int r = 0; r < 4; ++r) {
                int n = n0 + nloc + r;
                pk[r] = (n < N_TOK) ? (f16)acc[nf][8][r] : (f16)0.f;
            }
            *(f16x4*)(yT + (size_t)(wave*16 + col) * NPAD + n0 + nloc) = pk;
        }
    }
    __syncthreads();

    // ---- coalesced wT store: 512 e-rows x 64 n ----
    #pragma unroll
    for (int i = 0; i < 16; ++i) {
        int id = tid + i*256;                 // 4096 = 512 rows x 8 chunks(8 f16)
        int e = id >> 3, p = id & 7;
        f16x8 v = *(const f16x8*)(lT + (size_t)e*TPITCH + p*8);
        *(f16x8*)(wT + (size_t)e*NPAD + n0 + p*8) = v;
    }
}

// ---------------- K2: s_pre = sum_n w[n,e]*y[n,d]  (contiguous split-K x e-quarter) ----------------
#define K2_LOAD(AF, BF, kss)                                                         \
    {   int nb_ = (kss)*32 + quad*8;                                                 \
        _Pragma("unroll")                                                            \
        for (int v = 0; v < 4; ++v)                                                  \
            BF[v] = *(const f16x8*)(yT + (size_t)(v*16 + col)*NPAD + nb_);           \
        _Pragma("unroll")                                                            \
        for (int u = 0; u < 2; ++u)                                                  \
            AF[u] = *(const f16x8*)(wT + (size_t)(ebase + u*16 + col)*NPAD + nb_);   \
    }
#define K2_MFMA(AF, BF)                                                              \
    {   _Pragma("unroll")                                                            \
        for (int u = 0; u < 2; ++u) {                                                \
            _Pragma("unroll")                                                        \
            for (int v = 0; v < 4; ++v)                                              \
                acc[u][v] = __builtin_amdgcn_mfma_f32_16x16x32_f16(AF[u], BF[v], acc[u][v], 0, 0, 0); \
            float s_ = 0.f;                                                          \
            _Pragma("unroll")                                                        \
            for (int j = 0; j < 8; ++j) s_ += (float)AF[u][j];                       \
            dac[u] += s_;                                                            \
        }                                                                            \
    }
__launch_bounds__(256, 4)
__global__ void k2_spre(const f16* __restrict__ wT, const f16* __restrict__ yT,
                        float* __restrict__ spp, float* __restrict__ dpp) {
    const int tid = threadIdx.x, wave = tid >> 6, lane = tid & 63;
    const int quad = lane >> 4, col = lane & 15;
    const int slot = blockIdx.x >> 2, equad = blockIdx.x & 3;
    const int ebase = equad * 128 + wave * 32;

    const int ks0 = (slot * KSTEPS) >> 7;
    const int ks1 = ((slot + 1) * KSTEPS) >> 7;

    f32x4 acc[2][4];
    float dac[2];
    #pragma unroll
    for (int u = 0; u < 2; ++u) {
        dac[u] = 0.f;
        #pragma unroll
        for (int v = 0; v < 4; ++v) acc[u][v] = f32x4{0.f,0.f,0.f,0.f};
    }

    f16x8 afA[2], bfA[4], afB[2], bfB[4];
    K2_LOAD(afA, bfA, ks0)
    int ks = ks0;
    for (; ks + 2 <= ks1; ks += 2) {
        K2_LOAD(afB, bfB, ks + 1)
        K2_MFMA(afA, bfA)
        K2_LOAD(afA, bfA, ks + 2)   // one-step overread stays inside workspace; unused
        K2_MFMA(afB, bfB)
    }
    if (ks < ks1) K2_MFMA(afA, bfA)

    #pragma unroll
    for (int u = 0; u < 2; ++u) {
        dac[u] += __shfl_xor(dac[u], 16);
        dac[u] += __shfl_xor(dac[u], 32);
    }
    if (quad == 0) {
        #pragma unroll
        for (int u = 0; u < 2; ++u)
            dpp[slot*512 + ebase + u*16 + col] = dac[u];
    }
    float* dst = spp + (size_t)slot * 32768 + (size_t)equad * 8192;
    #pragma unroll
    for (int u = 0; u < 2; ++u)
        #pragma unroll
        for (int v = 0; v < 4; ++v)
            *(f32x4*)(dst + (size_t)((wave*2 + u)*4 + v)*256 + (size_t)lane*4) = acc[u][v];
}

// ---------------- K2r: reduce partials, de-swizzle frag order ----------------
__global__ void k2r_reduce(const float* __restrict__ spp, const float* __restrict__ dpp,
                           float* __restrict__ spre, float* __restrict__ dstd) {
    int i = blockIdx.x*256 + threadIdx.x;   // 32768
    float s = 0.f;
    for (int p = 0; p < K2SPL; ++p) s += spp[(size_t)p*32768 + i];
    int r = i & 3, L = (i >> 2) & 63, v = (i >> 8) & 3, g = (i >> 10) & 7, eq = (i >> 13) & 3;
    int e = eq*128 + (g >> 1)*32 + (g & 1)*16 + (L >> 4)*4 + r;
    int d = v*16 + (L & 15);
    spre[e*64 + d] = s;
    if (i < 512) {
        float tt = 0.f;
        for (int p = 0; p < K2SPL; ++p) tt += dpp[p*512 + i];
        dstd[i] = tt;
    }
}

// ---------------- K3: per-head middle block (exact fp32, all-LDS, 256 threads) ----------------
__global__ void k3_attn(const float* __restrict__ spre, const float* __restrict__ dstd,
                        const float* __restrict__ b1, const float* __restrict__ wq,
                        const float* __restrict__ wk, const float* __restrict__ wv,
                        const float* __restrict__ w3, const float* __restrict__ b3,
                        f16* __restrict__ sout) {
    __shared__ float wa[64][65], wb[64][65], wc[64][65];   // wq,wk,wv; wa reused for w3
    __shared__ float ss[64][65], qq[64][65], kk[64][65], vv[64][65], sc[64][65];
    const int h = blockIdx.x, tid = threadIdx.x;

    for (int i = tid; i < 4096; i += 256) {
        int r = i >> 6, c = i & 63;
        wa[r][c] = wq[i];
        wb[r][c] = wk[i];
        wc[r][c] = wv[i];
        ss[r][c] = spre[h*4096 + i] / (dstd[h*64 + r] + 1e-5f) + b1[c];
    }
    __syncthreads();

    #pragma unroll
    for (int it = 0; it < 16; ++it) {
        int m = it*4 + (tid >> 6), e = tid & 63;
        float aq = 0.f, ak = 0.f, av = 0.f;
        #pragma unroll 8
        for (int d = 0; d < 64; ++d) {
            float sv = ss[m][d];
            aq += sv * wa[e][d];
            ak += sv * wb[e][d];
            av += sv * wc[e][d];
        }
        qq[m][e] = aq; kk[m][e] = ak; vv[m][e] = av;
    }
    __syncthreads();

    for (int i = tid; i < 4096; i += 256) wa[i >> 6][i & 63] = w3[i];
    #pragma unroll
    for (int it = 0; it < 16; ++it) {
        int m = it*4 + (tid >> 6), l = tid & 63;
        float a = 0.f;
        #pragma unroll 8
        for (int e = 0; e < 64; ++e) a += qq[m][e] * kk[l][e];
        sc[m][l] = a * 0.125f;
    }
    __syncthreads();

    if (tid < 64) {
        int m = tid;
        float mx = -1e30f;
        #pragma unroll 8
        for (int l = 0; l < 64; ++l) mx = fmaxf(mx, sc[m][l]);
        float sm = 0.f;
        #pragma unroll 8
        for (int l = 0; l < 64; ++l) { float ev = __expf(sc[m][l] - mx); sc[m][l] = ev; sm += ev; }
        float rs = 1.0f / sm;
        #pragma unroll 8
        for (int l = 0; l < 64; ++l) sc[m][l] *= rs;
    }
    __syncthreads();

    #pragma unroll
    for (int it = 0; it < 16; ++it) {
        int m = it*4 + (tid >> 6), e = tid & 63;
        float a = 0.f;
        #pragma unroll 8
        for (int l = 0; l < 64; ++l) a += sc[m][l] * vv[l][e];
        ss[m][e] = a;
    }
    __syncthreads();

    #pragma unroll
    for (int it = 0; it < 16; ++it) {
        int d = it*4 + (tid >> 6), m = tid & 63;
        float a = b3[d];
        #pragma unroll 8
        for (int e = 0; e < 64; ++e) a += ss[m][e] * wa[d][e];
        sout[(h*64 + d)*64 + m] = (f16)a;
    }
}

// ---------------- K4: deslice x_out = w @ s_out (wT gather, 32-row tiles, 4 blocks/CU) ----------------
#define K4PITCH 36                               // f16; 72 B rows, <=2-way LDS banks
__launch_bounds__(256, 4)
__global__ void k4_deslice(const f16* __restrict__ wT, const f16* __restrict__ sout,
                           float* __restrict__ out) {
    __shared__ f16 ldsW[512 * K4PITCH];          // 36864 B
    const int tid = threadIdx.x, wave = tid >> 6, lane = tid & 63;
    const int quad = lane >> 4, col = lane & 15;
    const int n0 = blockIdx.x * 32;

    // stage wT[:, n0:n0+32] -> ldsW[e][nlocal]
    #pragma unroll
    for (int i = 0; i < 8; ++i) {
        int id = tid + i*256;               // 2048 = 512 rows x 4 chunks(8 f16 = 16 B)
        int e = id >> 2, p = id & 3;
        f16x8 v = *(const f16x8*)(wT + (size_t)e*NPAD + n0 + p*8);
        *(f16x8*)(ldsW + (size_t)e*K4PITCH + p*8) = v;
    }
    __syncthreads();

    f32x4 acc[2][2][4];
    #pragma unroll
    for (int hh = 0; hh < 2; ++hh)
        #pragma unroll
        for (int t = 0; t < 2; ++t)
            #pragma unroll
            for (int v = 0; v < 4; ++v) acc[hh][t][v] = f32x4{0.f,0.f,0.f,0.f};

    #pragma unroll
    for (int hh = 0; hh < 2; ++hh) {
        int h = wave*2 + hh;
        #pragma unroll
        for (int ks = 0; ks < 2; ++ks) {
            f16x8 af[2], bf[4];
            #pragma unroll
            for (int t = 0; t < 2; ++t) {
                f16x8 a;
                #pragma unroll
                for (int j = 0; j < 8; ++j)
                    a[j] = ldsW[(size_t)(h*64 + ks*32 + quad*8 + j)*K4PITCH + t*16 + col];
                af[t] = a;
            }
            #pragma unroll
            for (int v = 0; v < 4; ++v)
                bf[v] = *(const f16x8*)(sout + (size_t)(h*64 + v*16 + col)*64 + ks*32 + quad*8);
            #pragma unroll
            for (int t = 0; t < 2; ++t)
                #pragma unroll
                for (int v = 0; v < 4; ++v)
                    acc[hh][t][v] = __builtin_amdgcn_mfma_f32_16x16x32_f16(af[t], bf[v], acc[hh][t][v], 0, 0, 0);
        }
    }

    #pragma unroll
    for (int hh = 0; hh < 2; ++hh) {
        int h = wave*2 + hh;
        #pragma unroll
        for (int t = 0; t < 2; ++t)
            #pragma unroll
            for (int v = 0; v < 4; ++v)
                #pragma unroll
                for (int r = 0; r < 4; ++r) {
                    int n = n0 + t*16 + quad*4 + r;
                    if (n < N_TOK)
                        out[(size_t)n*512 + h*64 + v*16 + col] = acc[hh][t][v][r];
                }
    }
}

// ---------------- launcher ----------------
extern "C" void kernel_launch(void* const* d_in, const int* in_sizes, int n_in,
                              void* d_out, int out_size, void* d_ws, size_t ws_size,
                              hipStream_t stream) {
    const float* x           = (const float*)d_in[0];
    const float* temperature = (const float*)d_in[1];
    const float* w_slice     = (const float*)d_in[2];
    const float* b_slice     = (const float*)d_in[3];
    const float* w1          = (const float*)d_in[4];
    const float* b1          = (const float*)d_in[5];
    const float* wq          = (const float*)d_in[6];
    const float* wk          = (const float*)d_in[7];
    const float* wv          = (const float*)d_in[8];
    const float* w3          = (const float*)d_in[9];
    const float* b3          = (const float*)d_in[10];
    float* out = (float*)d_out;
    char*  ws  = (char*)d_ws;

    f16*   wT    = (f16*)(ws + O_WT);
    f16*   yT    = (f16*)(ws + O_YT);
    f16*   wfr   = (f16*)(ws + O_WFR);
    float* spp   = (float*)(ws + O_SPP);
    float* dpp   = (float*)(ws + O_DPP);
    float* spre  = (float*)(ws + O_SPRE);
    float* dstd  = (float*)(ws + O_DSTD);
    f16*   sout  = (f16*)(ws + O_SOUT);

    k0_pack<<<144, 256, 0, stream>>>(w_slice, w1, wfr);
    k1_slice<<<NT1, 256, 0, stream>>>(x, temperature, wfr, b_slice, wT, yT);
    k2_spre<<<K2SPL*4, 256, 0, stream>>>(wT, yT, spp, dpp);
    k2r_reduce<<<128, 256, 0, stream>>>(spp, dpp, spre, dstd);
    k3_attn<<<8, 256, 0, stream>>>(spre, dstd, b1, wq, wk, wv, w3, b3, sout);
    k4_deslice<<<KSTEPS, 256, 0, stream>>>(wT, sout, out);
}

// Round 5
// 579.670 us; speedup vs baseline: 1.1238x; 1.0328x over previous
//
#include <hip/hip_runtime.h>

typedef _Float16 f16;
typedef _Float16 f16x8 __attribute__((ext_vector_type(8)));
typedef _Float16 f16x4 __attribute__((ext_vector_type(4)));
typedef float    f32x4 __attribute__((ext_vector_type(4)));

#define N_TOK   100000
#define NPAD    100032         // 3126 * 32 = 1563 * 64
#define NT1     1563           // 64-row n-tiles
#define CDIM    512
#define KSTEPS  (NPAD/32)      // 3126
#define K2SPL   128            // split-K slots

// ---------------- workspace layout (bytes) ----------------
#define O_WT     ((size_t)0)                       // w^T fp16 [512][NPAD]
#define SZ_WT    ((size_t)512*NPAD*2)
#define O_YT     (O_WT + SZ_WT)                    // y^T fp16 [64][NPAD]
#define SZ_YT    ((size_t)64*NPAD*2)
#define O_WFR    (O_YT + SZ_YT)                    // frag-linear W+w1 fp16
#define SZ_WFR   ((size_t)16*4*9*64*8*2)
#define O_SPP    (O_WFR + SZ_WFR)                  // s_pre partials [128][32768] f32
#define SZ_SPP   ((size_t)K2SPL*32768*4)
#define O_DPP    (O_SPP + SZ_SPP)                  // d partials [128][512] f32
#define SZ_DPP   ((size_t)K2SPL*512*4)
#define O_SPRE   (O_DPP + SZ_DPP)                  // s_pre [512][64] f32
#define SZ_SPRE  ((size_t)32768*4)
#define O_DSTD   (O_SPRE + SZ_SPRE)                // d [512] f32
#define SZ_DSTD  ((size_t)512*4)
#define O_SOUT   (O_DSTD + SZ_DSTD)                // s_out^T fp16 [8][64dh][64m]
#define SZ_SOUT  ((size_t)8*64*64*2)

// ---------------- K0: pack W = [w_slice; w1] (576x512) into MFMA-fragment-linear fp16 ----------------
__global__ void k0_pack(const float* __restrict__ wsf, const float* __restrict__ w1f,
                        f16* __restrict__ wfr) {
    int c = blockIdx.x * 256 + threadIdx.x;      // 36864 chunks total
    int lane = c & 63, g = c >> 6;               // g in 0..575
    int u  = g % 9,  r = g / 9;                  // r in 0..63
    int we = r & 3,  kg = r >> 2;
    int col = lane & 15, quad = lane >> 4;
    int k = kg * 32 + quad * 8;
    const float* src;
    if (u < 8) src = wsf + (size_t)(we*128 + u*16 + col) * CDIM + k;
    else       src = w1f + (size_t)(we*16  + col) * CDIM + k;
    float4 a = *(const float4*)(src);
    float4 b = *(const float4*)(src + 4);
    f16x8 h;
    h[0]=(f16)a.x; h[1]=(f16)a.y; h[2]=(f16)a.z; h[3]=(f16)a.w;
    h[4]=(f16)b.x; h[5]=(f16)b.y; h[6]=(f16)b.z; h[7]=(f16)b.w;
    *(f16x8*)(wfr + (size_t)c * 8) = h;
}

// ---------------- K1: slice GEMM + softmax + y GEMM (e-split for occupancy) ----------------
// grid = 2*NT1: bid = ntile*2 + hgrp. Block = 4 waves; wave owns ONE head
// (h = hgrp*4+wave, 64 e-cols); hgrp==0 blocks also compute y (frag u==8).
// acc[4][5] = 80 regs -> 3 waves/SIMD (was 144 regs / 2 waves).
#define XROW 40
#define TPITCH 72                                // wT stage pitch (f16)
__launch_bounds__(256, 3)
__global__ void k1_slice(const float* __restrict__ x, const float* __restrict__ temperature,
                         const f16* __restrict__ wfr, const float* __restrict__ bsl,
                         f16* __restrict__ wT, f16* __restrict__ yT) {
    __shared__ f16 smem[256 * TPITCH];           // 36864 B, aliased 2 ways
    f16* lX = smem;                               // [2][64*XROW] = 10240 B
    f16* lT = smem;                               // [256][TPITCH]

    const int tid  = threadIdx.x;
    const int wave = tid >> 6;
    const int lane = tid & 63;
    const int quad = lane >> 4;
    const int col  = lane & 15;
    const int hgrp = blockIdx.x & 1;
    const int n0   = (blockIdx.x >> 1) * 64;
    const int h    = hgrp * 4 + wave;            // head owned by this wave

    const int srow = tid >> 2, sch = tid & 3;
    int snr = n0 + srow; if (snr > N_TOK - 1) snr = N_TOK - 1;
    const float* sbase = x + (size_t)snr * CDIM + sch * 8;

    {
        float4 a = *(const float4*)(sbase);
        float4 b = *(const float4*)(sbase + 4);
        f16x8 hh;
        hh[0]=(f16)a.x; hh[1]=(f16)a.y; hh[2]=(f16)a.z; hh[3]=(f16)a.w;
        hh[4]=(f16)b.x; hh[5]=(f16)b.y; hh[6]=(f16)b.z; hh[7]=(f16)b.w;
        *(f16x8*)(&lX[srow * XROW + sch * 8]) = hh;
    }

    f32x4 acc[4][5];
    #pragma unroll
    for (int nf = 0; nf < 4; ++nf)
        #pragma unroll
        for (int u = 0; u < 5; ++u) acc[nf][u] = f32x4{0.f,0.f,0.f,0.f};

    __syncthreads();

    #pragma unroll 2
    for (int kg = 0; kg < 16; ++kg) {
        // 4 slice frags for head h: wfr[(kg*4 + h/2)*9 + (h&1)*4 + j]
        const f16* wb = wfr + ((size_t)(kg*4 + (h >> 1)) * 9 + (size_t)(h & 1) * 4) * 512
                            + (size_t)lane * 8;
        f16x8 bf[4];
        #pragma unroll
        for (int j = 0; j < 4; ++j) bf[j] = *(const f16x8*)(wb + j * 512);
        f16x8 bfy;
        if (hgrp == 0)
            bfy = *(const f16x8*)(wfr + ((size_t)(kg*4 + wave) * 9 + 8) * 512 + (size_t)lane * 8);

        float4 xa, xb;
        if (kg < 15) {
            xa = *(const float4*)(sbase + (kg + 1) * 32);
            xb = *(const float4*)(sbase + (kg + 1) * 32 + 4);
        }

        const f16* xbuf = lX + (kg & 1) * (64 * XROW);
        f16x8 af[4];
        #pragma unroll
        for (int nf = 0; nf < 4; ++nf)
            af[nf] = *(const f16x8*)(xbuf + (nf*16 + col) * XROW + quad * 8);

        #pragma unroll
        for (int nf = 0; nf < 4; ++nf)
            #pragma unroll
            for (int j = 0; j < 4; ++j)
                acc[nf][j] = __builtin_amdgcn_mfma_f32_16x16x32_f16(af[nf], bf[j], acc[nf][j], 0, 0, 0);
        if (hgrp == 0) {
            #pragma unroll
            for (int nf = 0; nf < 4; ++nf)
                acc[nf][4] = __builtin_amdgcn_mfma_f32_16x16x32_f16(af[nf], bfy, acc[nf][4], 0, 0, 0);
        }

        if (kg < 15) {
            f16x8 hh;
            hh[0]=(f16)xa.x; hh[1]=(f16)xa.y; hh[2]=(f16)xa.z; hh[3]=(f16)xa.w;
            hh[4]=(f16)xb.x; hh[5]=(f16)xb.y; hh[6]=(f16)xb.z; hh[7]=(f16)xb.w;
            *(f16x8*)(&lX[((kg + 1) & 1) * (64 * XROW) + srow * XROW + sch * 8]) = hh;
        }
        __syncthreads();
    }

    // ---- bias + temperature (one head per wave) ----
    #pragma unroll
    for (int j = 0; j < 4; ++j) {
        float b = bsl[h*64 + j*16 + col];
        #pragma unroll
        for (int nf = 0; nf < 4; ++nf)
            #pragma unroll
            for (int r = 0; r < 4; ++r) acc[nf][j][r] += b;
    }
    float tv = temperature[h];
    tv = fminf(fmaxf(tv, 0.1f), 5.0f);
    const float invt = 1.0f / tv;

    // ---- softmax over M=64 (4 frags x 16 cols); wT staged to LDS ----
    #pragma unroll
    for (int nf = 0; nf < 4; ++nf) {
        const int nloc = nf*16 + quad*4;
        float mx[4];
        #pragma unroll
        for (int r = 0; r < 4; ++r) {
            float m01 = fmaxf(acc[nf][0][r], acc[nf][1][r]);
            float m23 = fmaxf(acc[nf][2][r], acc[nf][3][r]);
            mx[r] = fmaxf(m01, m23);
        }
        #pragma unroll
        for (int d = 1; d < 16; d <<= 1)
            #pragma unroll
            for (int r = 0; r < 4; ++r) mx[r] = fmaxf(mx[r], __shfl_xor(mx[r], d));
        float sm[4] = {0.f, 0.f, 0.f, 0.f};
        #pragma unroll
        for (int j = 0; j < 4; ++j)
            #pragma unroll
            for (int r = 0; r < 4; ++r) {
                float ev = __expf((acc[nf][j][r] - mx[r]) * invt);
                acc[nf][j][r] = ev;
                sm[r] += ev;
            }
        #pragma unroll
        for (int d = 1; d < 16; d <<= 1)
            #pragma unroll
            for (int r = 0; r < 4; ++r) sm[r] += __shfl_xor(sm[r], d);
        #pragma unroll
        for (int r = 0; r < 4; ++r) sm[r] = 1.0f / sm[r];
        #pragma unroll
        for (int j = 0; j < 4; ++j) {
            f16x4 pk;
            #pragma unroll
            for (int r = 0; r < 4; ++r) {
                int n = n0 + nloc + r;
                float wv = (n < N_TOK) ? acc[nf][j][r] * sm[r] : 0.0f;
                pk[r] = (f16)wv;
            }
            int e_loc = wave*64 + j*16 + col;        // local e within block's 256
            *(f16x4*)(lT + (size_t)e_loc*TPITCH + nloc) = pk;
        }
        if (hgrp == 0) {
            f16x4 pk;
            #pragma unroll
            for (int r = 0; r < 4; ++r) {
                int n = n0 + nloc + r;
                pk[r] = (n < N_TOK) ? (f16)acc[nf][4][r] : (f16)0.f;
            }
            *(f16x4*)(yT + (size_t)(wave*16 + col) * NPAD + n0 + nloc) = pk;
        }
    }
    __syncthreads();

    // ---- coalesced wT store: 256 e-rows x 64 n ----
    #pragma unroll
    for (int i = 0; i < 8; ++i) {
        int id = tid + i*256;                 // 2048 = 256 rows x 8 chunks(8 f16)
        int e = id >> 3, p = id & 7;
        f16x8 v = *(const f16x8*)(lT + (size_t)e*TPITCH + p*8);
        *(f16x8*)(wT + (size_t)(hgrp*256 + e)*NPAD + n0 + p*8) = v;
    }
}

// ---------------- K2: s_pre = sum_n w[n,e]*y[n,d]  (contiguous split-K x e-quarter) ----------------
#define K2_LOAD(AF, BF, kss)                                                         \
    {   int nb_ = (kss)*32 + quad*8;                                                 \
        _Pragma("unroll")                                                            \
        for (int v = 0; v < 4; ++v)                                                  \
            BF[v] = *(const f16x8*)(yT + (size_t)(v*16 + col)*NPAD + nb_);           \
        _Pragma("unroll")                                                            \
        for (int u = 0; u < 2; ++u)                                                  \
            AF[u] = *(const f16x8*)(wT + (size_t)(ebase + u*16 + col)*NPAD + nb_);   \
    }
#define K2_MFMA(AF, BF)                                                              \
    {   _Pragma("unroll")                                                            \
        for (int u = 0; u < 2; ++u) {                                                \
            _Pragma("unroll")                                                        \
            for (int v = 0; v < 4; ++v)                                              \
                acc[u][v] = __builtin_amdgcn_mfma_f32_16x16x32_f16(AF[u], BF[v], acc[u][v], 0, 0, 0); \
            float s_ = 0.f;                                                          \
            _Pragma("unroll")                                                        \
            for (int j = 0; j < 8; ++j) s_ += (float)AF[u][j];                       \
            dac[u] += s_;                                                            \
        }                                                                            \
    }
__launch_bounds__(256, 4)
__global__ void k2_spre(const f16* __restrict__ wT, const f16* __restrict__ yT,
                        float* __restrict__ spp, float* __restrict__ dpp) {
    const int tid = threadIdx.x, wave = tid >> 6, lane = tid & 63;
    const int quad = lane >> 4, col = lane & 15;
    const int slot = blockIdx.x >> 2, equad = blockIdx.x & 3;
    const int ebase = equad * 128 + wave * 32;

    const int ks0 = (slot * KSTEPS) >> 7;
    const int ks1 = ((slot + 1) * KSTEPS) >> 7;

    f32x4 acc[2][4];
    float dac[2];
    #pragma unroll
    for (int u = 0; u < 2; ++u) {
        dac[u] = 0.f;
        #pragma unroll
        for (int v = 0; v < 4; ++v) acc[u][v] = f32x4{0.f,0.f,0.f,0.f};
    }

    f16x8 afA[2], bfA[4], afB[2], bfB[4];
    K2_LOAD(afA, bfA, ks0)
    int ks = ks0;
    for (; ks + 2 <= ks1; ks += 2) {
        K2_LOAD(afB, bfB, ks + 1)
        K2_MFMA(afA, bfA)
        K2_LOAD(afA, bfA, ks + 2)   // one-step overread stays inside workspace; unused
        K2_MFMA(afB, bfB)
    }
    if (ks < ks1) K2_MFMA(afA, bfA)

    #pragma unroll
    for (int u = 0; u < 2; ++u) {
        dac[u] += __shfl_xor(dac[u], 16);
        dac[u] += __shfl_xor(dac[u], 32);
    }
    if (quad == 0) {
        #pragma unroll
        for (int u = 0; u < 2; ++u)
            dpp[slot*512 + ebase + u*16 + col] = dac[u];
    }
    float* dst = spp + (size_t)slot * 32768 + (size_t)equad * 8192;
    #pragma unroll
    for (int u = 0; u < 2; ++u)
        #pragma unroll
        for (int v = 0; v < 4; ++v)
            *(f32x4*)(dst + (size_t)((wave*2 + u)*4 + v)*256 + (size_t)lane*4) = acc[u][v];
}

// ---------------- K2r: reduce partials, de-swizzle frag order ----------------
__global__ void k2r_reduce(const float* __restrict__ spp, const float* __restrict__ dpp,
                           float* __restrict__ spre, float* __restrict__ dstd) {
    int i = blockIdx.x*256 + threadIdx.x;   // 32768
    float s = 0.f;
    for (int p = 0; p < K2SPL; ++p) s += spp[(size_t)p*32768 + i];
    int r = i & 3, L = (i >> 2) & 63, v = (i >> 8) & 3, g = (i >> 10) & 7, eq = (i >> 13) & 3;
    int e = eq*128 + (g >> 1)*32 + (g & 1)*16 + (L >> 4)*4 + r;
    int d = v*16 + (L & 15);
    spre[e*64 + d] = s;
    if (i < 512) {
        float tt = 0.f;
        for (int p = 0; p < K2SPL; ++p) tt += dpp[p*512 + i];
        dstd[i] = tt;
    }
}

// ---------------- K3: per-head middle block, m-split 4 ways (grid 32) ----------------
// block = (head h, m-slice ms of 16 rows). kk/vv computed full (needed by all),
// qq/scores/softmax/s_att/sout only for the slice -> ~2x less serial LDS work, 4x CUs.
__global__ void k3_attn(const float* __restrict__ spre, const float* __restrict__ dstd,
                        const float* __restrict__ b1, const float* __restrict__ wq,
                        const float* __restrict__ wk, const float* __restrict__ wv,
                        const float* __restrict__ w3, const float* __restrict__ b3,
                        f16* __restrict__ sout) {
    __shared__ float wa[64][65], wb[64][65], wc[64][65];   // wq,wk,wv; wa reused for w3
    __shared__ float ss[64][65], kk[64][65], vv[64][65];
    __shared__ float qq[16][65], sc[16][65];               // slice-local
    const int h = blockIdx.x >> 2, ms = blockIdx.x & 3, tid = threadIdx.x;

    for (int i = tid; i < 4096; i += 256) {
        int r = i >> 6, c = i & 63;
        wa[r][c] = wq[i];
        wb[r][c] = wk[i];
        wc[r][c] = wv[i];
        ss[r][c] = spre[h*4096 + i] / (dstd[h*64 + r] + 1e-5f) + b1[c];
    }
    __syncthreads();

    // k, v full (64 rows)
    #pragma unroll
    for (int it = 0; it < 16; ++it) {
        int m = it*4 + (tid >> 6), e = tid & 63;
        float ak = 0.f, av = 0.f;
        #pragma unroll 8
        for (int d = 0; d < 64; ++d) {
            float sv = ss[m][d];
            ak += sv * wb[e][d];
            av += sv * wc[e][d];
        }
        kk[m][e] = ak; vv[m][e] = av;
    }
    // q: slice only (16 rows)
    #pragma unroll
    for (int it = 0; it < 4; ++it) {
        int ml = it*4 + (tid >> 6), e = tid & 63;
        float aq = 0.f;
        #pragma unroll 8
        for (int d = 0; d < 64; ++d) aq += ss[ms*16 + ml][d] * wa[e][d];
        qq[ml][e] = aq;
    }
    __syncthreads();

    // scores (slice); stage w3 into wa (wq dead after qq)
    for (int i = tid; i < 4096; i += 256) wa[i >> 6][i & 63] = w3[i];
    #pragma unroll
    for (int it = 0; it < 4; ++it) {
        int ml = it*4 + (tid >> 6), l = tid & 63;
        float a = 0.f;
        #pragma unroll 8
        for (int e = 0; e < 64; ++e) a += qq[ml][e] * kk[l][e];
        sc[ml][l] = a * 0.125f;
    }
    __syncthreads();

    // softmax rows (slice)
    if (tid < 16) {
        int ml = tid;
        float mx = -1e30f;
        #pragma unroll 8
        for (int l = 0; l < 64; ++l) mx = fmaxf(mx, sc[ml][l]);
        float sm = 0.f;
        #pragma unroll 8
        for (int l = 0; l < 64; ++l) { float ev = __expf(sc[ml][l] - mx); sc[ml][l] = ev; sm += ev; }
        float rs = 1.0f / sm;
        #pragma unroll 8
        for (int l = 0; l < 64; ++l) sc[ml][l] *= rs;
    }
    __syncthreads();

    // s_att (slice) -> qq (dead after scores)
    #pragma unroll
    for (int it = 0; it < 4; ++it) {
        int ml = it*4 + (tid >> 6), e = tid & 63;
        float a = 0.f;
        #pragma unroll 8
        for (int l = 0; l < 64; ++l) a += sc[ml][l] * vv[l][e];
        qq[ml][e] = a;
    }
    __syncthreads();

    // s_out^T slice: all d, 16 m; contiguous m-stores
    #pragma unroll
    for (int it = 0; it < 4; ++it) {
        int d = it*16 + (tid >> 4), ml = tid & 15;
        float a = b3[d];
        #pragma unroll 8
        for (int e = 0; e < 64; ++e) a += qq[ml][e] * wa[d][e];
        sout[(h*64 + d)*64 + ms*16 + ml] = (f16)a;
    }
}

// ---------------- K4: deslice x_out = w @ s_out (wT gather, XCD-swizzled) ----------------
#define K4PITCH 36                               // f16; 72 B rows, <=2-way LDS banks
__launch_bounds__(256, 4)
__global__ void k4_deslice(const f16* __restrict__ wT, const f16* __restrict__ sout,
                           float* __restrict__ out) {
    __shared__ f16 ldsW[512 * K4PITCH];          // 36864 B
    const int tid = threadIdx.x, wave = tid >> 6, lane = tid & 63;
    const int quad = lane >> 4, col = lane & 15;

    // bijective XCD swizzle (nwg = 3126 = 8*390 + 6): neighbors share wT lines -> same XCD
    const int bid = blockIdx.x;
    const int xcd = bid & 7, idx = bid >> 3;
    const int q = KSTEPS >> 3, r = KSTEPS & 7;   // 390, 6
    const int swz = (xcd < r ? xcd*(q+1) : r*(q+1) + (xcd - r)*q) + idx;
    const int n0 = swz * 32;

    // stage wT[:, n0:n0+32] -> ldsW[e][nlocal]
    #pragma unroll
    for (int i = 0; i < 8; ++i) {
        int id = tid + i*256;               // 2048 = 512 rows x 4 chunks(8 f16 = 16 B)
        int e = id >> 2, p = id & 3;
        f16x8 v = *(const f16x8*)(wT + (size_t)e*NPAD + n0 + p*8);
        *(f16x8*)(ldsW + (size_t)e*K4PITCH + p*8) = v;
    }
    __syncthreads();

    f32x4 acc[2][2][4];
    #pragma unroll
    for (int hh = 0; hh < 2; ++hh)
        #pragma unroll
        for (int t = 0; t < 2; ++t)
            #pragma unroll
            for (int v = 0; v < 4; ++v) acc[hh][t][v] = f32x4{0.f,0.f,0.f,0.f};

    #pragma unroll
    for (int hh = 0; hh < 2; ++hh) {
        int h = wave*2 + hh;
        #pragma unroll
        for (int ks = 0; ks < 2; ++ks) {
            f16x8 af[2], bf[4];
            #pragma unroll
            for (int t = 0; t < 2; ++t) {
                f16x8 a;
                #pragma unroll
                for (int j = 0; j < 8; ++j)
                    a[j] = ldsW[(size_t)(h*64 + ks*32 + quad*8 + j)*K4PITCH + t*16 + col];
                af[t] = a;
            }
            #pragma unroll
            for (int v = 0; v < 4; ++v)
                bf[v] = *(const f16x8*)(sout + (size_t)(h*64 + v*16 + col)*64 + ks*32 + quad*8);
            #pragma unroll
            for (int t = 0; t < 2; ++t)
                #pragma unroll
                for (int v = 0; v < 4; ++v)
                    acc[hh][t][v] = __builtin_amdgcn_mfma_f32_16x16x32_f16(af[t], bf[v], acc[hh][t][v], 0, 0, 0);
        }
    }

    #pragma unroll
    for (int hh = 0; hh < 2; ++hh) {
        int h = wave*2 + hh;
        #pragma unroll
        for (int t = 0; t < 2; ++t)
            #pragma unroll
            for (int v = 0; v < 4; ++v)
                #pragma unroll
                for (int r2 = 0; r2 < 4; ++r2) {
                    int n = n0 + t*16 + quad*4 + r2;
                    if (n < N_TOK)
                        out[(size_t)n*512 + h*64 + v*16 + col] = acc[hh][t][v][r2];
                }
    }
}

// ---------------- launcher ----------------
extern "C" void kernel_launch(void* const* d_in, const int* in_sizes, int n_in,
                              void* d_out, int out_size, void* d_ws, size_t ws_size,
                              hipStream_t stream) {
    const float* x           = (const float*)d_in[0];
    const float* temperature = (const float*)d_in[1];
    const float* w_slice     = (const float*)d_in[2];
    const float* b_slice     = (const float*)d_in[3];
    const float* w1          = (const float*)d_in[4];
    const float* b1          = (const float*)d_in[5];
    const float* wq          = (const float*)d_in[6];
    const float* wk          = (const float*)d_in[7];
    const float* wv          = (const float*)d_in[8];
    const float* w3          = (const float*)d_in[9];
    const float* b3          = (const float*)d_in[10];
    float* out = (float*)d_out;
    char*  ws  = (char*)d_ws;

    f16*   wT    = (f16*)(ws + O_WT);
    f16*   yT    = (f16*)(ws + O_YT);
    f16*   wfr   = (f16*)(ws + O_WFR);
    float* spp   = (float*)(ws + O_SPP);
    float* dpp   = (float*)(ws + O_DPP);
    float* spre  = (float*)(ws + O_SPRE);
    float* dstd  = (float*)(ws + O_DSTD);
    f16*   sout  = (f16*)(ws + O_SOUT);

    k0_pack<<<144, 256, 0, stream>>>(w_slice, w1, wfr);
    k1_slice<<<NT1*2, 256, 0, stream>>>(x, temperature, wfr, b_slice, wT, yT);
    k2_spre<<<K2SPL*4, 256, 0, stream>>>(wT, yT, spp, dpp);
    k2r_reduce<<<128, 256, 0, stream>>>(spp, dpp, spre, dstd);
    k3_attn<<<32, 256, 0, stream>>>(spre, dstd, b1, wq, wk, wv, w3, b3, sout);
    k4_deslice<<<KSTEPS, 256, 0, stream>>>(wT, sout, out);
}

// Round 6
// 563.009 us; speedup vs baseline: 1.1571x; 1.0296x over previous
//
#include <hip/hip_runtime.h>

typedef _Float16 f16;
typedef _Float16 f16x8 __attribute__((ext_vector_type(8)));
typedef _Float16 f16x4 __attribute__((ext_vector_type(4)));
typedef float    f32x4 __attribute__((ext_vector_type(4)));

#define N_TOK   100000
#define NPAD    100032         // 3126 * 32 = 1563 * 64
#define NT1     1563           // 64-row n-tiles
#define CDIM    512
#define KSTEPS  (NPAD/32)      // 3126
#define K2SPL   128            // split-K slots

// ---------------- workspace layout (bytes) ----------------
#define O_WT     ((size_t)0)                       // w^T fp16 [512][NPAD]
#define SZ_WT    ((size_t)512*NPAD*2)
#define O_YT     (O_WT + SZ_WT)                    // y^T fp16 [64][NPAD]
#define SZ_YT    ((size_t)64*NPAD*2)
#define O_WFR    (O_YT + SZ_YT)                    // frag-linear W+w1 fp16
#define SZ_WFR   ((size_t)16*4*9*64*8*2)
#define O_SPP    (O_WFR + SZ_WFR)                  // s_pre partials [128][32768] f32
#define SZ_SPP   ((size_t)K2SPL*32768*4)
#define O_DPP    (O_SPP + SZ_SPP)                  // d partials [128][512] f32
#define SZ_DPP   ((size_t)K2SPL*512*4)
#define O_SPRE   (O_DPP + SZ_DPP)                  // s_pre [512][64] f32
#define SZ_SPRE  ((size_t)32768*4)
#define O_DSTD   (O_SPRE + SZ_SPRE)                // d [512] f32
#define SZ_DSTD  ((size_t)512*4)
#define O_SOUT   (O_DSTD + SZ_DSTD)                // s_out^T fp16 [8][64dh][64m]
#define SZ_SOUT  ((size_t)8*64*64*2)

// ---------------- K0: pack W = [w_slice; w1] (576x512) into MFMA-fragment-linear fp16 ----------------
__global__ void k0_pack(const float* __restrict__ wsf, const float* __restrict__ w1f,
                        f16* __restrict__ wfr) {
    int c = blockIdx.x * 256 + threadIdx.x;      // 36864 chunks total
    int lane = c & 63, g = c >> 6;               // g in 0..575
    int u  = g % 9,  r = g / 9;                  // r in 0..63
    int we = r & 3,  kg = r >> 2;
    int col = lane & 15, quad = lane >> 4;
    int k = kg * 32 + quad * 8;
    const float* src;
    if (u < 8) src = wsf + (size_t)(we*128 + u*16 + col) * CDIM + k;
    else       src = w1f + (size_t)(we*16  + col) * CDIM + k;
    float4 a = *(const float4*)(src);
    float4 b = *(const float4*)(src + 4);
    f16x8 h;
    h[0]=(f16)a.x; h[1]=(f16)a.y; h[2]=(f16)a.z; h[3]=(f16)a.w;
    h[4]=(f16)b.x; h[5]=(f16)b.y; h[6]=(f16)b.z; h[7]=(f16)b.w;
    *(f16x8*)(wfr + (size_t)c * 8) = h;
}

// ---------------- K1: slice GEMM + softmax + y GEMM (e-split, XCD-paired) ----------------
// grid = 2*NT1. XCD pairing: the two hgrp-blocks of one n-tile are mapped 8 apart
// (same bid mod 8 -> same XCD) so the second x-tile read hits that XCD's L2.
#define XROW 40
#define TPITCH 72                                // wT stage pitch (f16)
__launch_bounds__(256, 3)
__global__ void k1_slice(const float* __restrict__ x, const float* __restrict__ temperature,
                         const f16* __restrict__ wfr, const float* __restrict__ bsl,
                         f16* __restrict__ wT, f16* __restrict__ yT) {
    __shared__ f16 smem[256 * TPITCH];           // 36864 B, aliased 2 ways
    f16* lX = smem;                               // [2][64*XROW] = 10240 B
    f16* lT = smem;                               // [256][TPITCH]

    const int tid  = threadIdx.x;
    const int wave = tid >> 6;
    const int lane = tid & 63;
    const int quad = lane >> 4;
    const int col  = lane & 15;

    // bid -> (ntile, hgrp): pairs land on the same XCD (bid and bid+8)
    const int b = blockIdx.x;
    int nt, hg;
    if (b < 3120) { nt = (b >> 4) * 8 + (b & 7); hg = (b >> 3) & 1; }
    else          { nt = 1560 + ((b - 3120) >> 1); hg = (b - 3120) & 1; }
    const int hgrp = hg;
    const int n0   = nt * 64;
    const int h    = hgrp * 4 + wave;            // head owned by this wave

    const int srow = tid >> 2, sch = tid & 3;
    int snr = n0 + srow; if (snr > N_TOK - 1) snr = N_TOK - 1;
    const float* sbase = x + (size_t)snr * CDIM + sch * 8;

    {
        float4 a = *(const float4*)(sbase);
        float4 bb = *(const float4*)(sbase + 4);
        f16x8 hh;
        hh[0]=(f16)a.x; hh[1]=(f16)a.y; hh[2]=(f16)a.z; hh[3]=(f16)a.w;
        hh[4]=(f16)bb.x; hh[5]=(f16)bb.y; hh[6]=(f16)bb.z; hh[7]=(f16)bb.w;
        *(f16x8*)(&lX[srow * XROW + sch * 8]) = hh;
    }

    f32x4 acc[4][5];
    #pragma unroll
    for (int nf = 0; nf < 4; ++nf)
        #pragma unroll
        for (int u = 0; u < 5; ++u) acc[nf][u] = f32x4{0.f,0.f,0.f,0.f};

    __syncthreads();

    #pragma unroll 2
    for (int kg = 0; kg < 16; ++kg) {
        const f16* wb = wfr + ((size_t)(kg*4 + (h >> 1)) * 9 + (size_t)(h & 1) * 4) * 512
                            + (size_t)lane * 8;
        f16x8 bf[4];
        #pragma unroll
        for (int j = 0; j < 4; ++j) bf[j] = *(const f16x8*)(wb + j * 512);
        f16x8 bfy;
        if (hgrp == 0)
            bfy = *(const f16x8*)(wfr + ((size_t)(kg*4 + wave) * 9 + 8) * 512 + (size_t)lane * 8);

        float4 xa, xb;
        if (kg < 15) {
            xa = *(const float4*)(sbase + (kg + 1) * 32);
            xb = *(const float4*)(sbase + (kg + 1) * 32 + 4);
        }

        const f16* xbuf = lX + (kg & 1) * (64 * XROW);
        f16x8 af[4];
        #pragma unroll
        for (int nf = 0; nf < 4; ++nf)
            af[nf] = *(const f16x8*)(xbuf + (nf*16 + col) * XROW + quad * 8);

        #pragma unroll
        for (int nf = 0; nf < 4; ++nf)
            #pragma unroll
            for (int j = 0; j < 4; ++j)
                acc[nf][j] = __builtin_amdgcn_mfma_f32_16x16x32_f16(af[nf], bf[j], acc[nf][j], 0, 0, 0);
        if (hgrp == 0) {
            #pragma unroll
            for (int nf = 0; nf < 4; ++nf)
                acc[nf][4] = __builtin_amdgcn_mfma_f32_16x16x32_f16(af[nf], bfy, acc[nf][4], 0, 0, 0);
        }

        if (kg < 15) {
            f16x8 hh;
            hh[0]=(f16)xa.x; hh[1]=(f16)xa.y; hh[2]=(f16)xa.z; hh[3]=(f16)xa.w;
            hh[4]=(f16)xb.x; hh[5]=(f16)xb.y; hh[6]=(f16)xb.z; hh[7]=(f16)xb.w;
            *(f16x8*)(&lX[((kg + 1) & 1) * (64 * XROW) + srow * XROW + sch * 8]) = hh;
        }
        __syncthreads();
    }

    // ---- bias + temperature (one head per wave) ----
    #pragma unroll
    for (int j = 0; j < 4; ++j) {
        float bb = bsl[h*64 + j*16 + col];
        #pragma unroll
        for (int nf = 0; nf < 4; ++nf)
            #pragma unroll
            for (int r = 0; r < 4; ++r) acc[nf][j][r] += bb;
    }
    float tv = temperature[h];
    tv = fminf(fmaxf(tv, 0.1f), 5.0f);
    const float invt = 1.0f / tv;

    // ---- softmax over M=64 (4 frags x 16 cols); wT staged to LDS ----
    #pragma unroll
    for (int nf = 0; nf < 4; ++nf) {
        const int nloc = nf*16 + quad*4;
        float mx[4];
        #pragma unroll
        for (int r = 0; r < 4; ++r) {
            float m01 = fmaxf(acc[nf][0][r], acc[nf][1][r]);
            float m23 = fmaxf(acc[nf][2][r], acc[nf][3][r]);
            mx[r] = fmaxf(m01, m23);
        }
        #pragma unroll
        for (int d = 1; d < 16; d <<= 1)
            #pragma unroll
            for (int r = 0; r < 4; ++r) mx[r] = fmaxf(mx[r], __shfl_xor(mx[r], d));
        float sm[4] = {0.f, 0.f, 0.f, 0.f};
        #pragma unroll
        for (int j = 0; j < 4; ++j)
            #pragma unroll
            for (int r = 0; r < 4; ++r) {
                float ev = __expf((acc[nf][j][r] - mx[r]) * invt);
                acc[nf][j][r] = ev;
                sm[r] += ev;
            }
        #pragma unroll
        for (int d = 1; d < 16; d <<= 1)
            #pragma unroll
            for (int r = 0; r < 4; ++r) sm[r] += __shfl_xor(sm[r], d);
        #pragma unroll
        for (int r = 0; r < 4; ++r) sm[r] = 1.0f / sm[r];
        #pragma unroll
        for (int j = 0; j < 4; ++j) {
            f16x4 pk;
            #pragma unroll
            for (int r = 0; r < 4; ++r) {
                int n = n0 + nloc + r;
                float wv = (n < N_TOK) ? acc[nf][j][r] * sm[r] : 0.0f;
                pk[r] = (f16)wv;
            }
            int e_loc = wave*64 + j*16 + col;        // local e within block's 256
            *(f16x4*)(lT + (size_t)e_loc*TPITCH + nloc) = pk;
        }
        if (hgrp == 0) {
            f16x4 pk;
            #pragma unroll
            for (int r = 0; r < 4; ++r) {
                int n = n0 + nloc + r;
                pk[r] = (n < N_TOK) ? (f16)acc[nf][4][r] : (f16)0.f;
            }
            *(f16x4*)(yT + (size_t)(wave*16 + col) * NPAD + n0 + nloc) = pk;
        }
    }
    __syncthreads();

    // ---- coalesced wT store: 256 e-rows x 64 n ----
    #pragma unroll
    for (int i = 0; i < 8; ++i) {
        int id = tid + i*256;                 // 2048 = 256 rows x 8 chunks(8 f16)
        int e = id >> 3, p = id & 7;
        f16x8 v = *(const f16x8*)(lT + (size_t)e*TPITCH + p*8);
        *(f16x8*)(wT + (size_t)(hgrp*256 + e)*NPAD + n0 + p*8) = v;
    }
}

// ---------------- K2: s_pre = sum_n w[n,e]*y[n,d]  (contiguous split-K x e-quarter) ----------------
#define K2_LOAD(AF, BF, kss)                                                         \
    {   int nb_ = (kss)*32 + quad*8;                                                 \
        _Pragma("unroll")                                                            \
        for (int v = 0; v < 4; ++v)                                                  \
            BF[v] = *(const f16x8*)(yT + (size_t)(v*16 + col)*NPAD + nb_);           \
        _Pragma("unroll")                                                            \
        for (int u = 0; u < 2; ++u)                                                  \
            AF[u] = *(const f16x8*)(wT + (size_t)(ebase + u*16 + col)*NPAD + nb_);   \
    }
#define K2_MFMA(AF, BF)                                                              \
    {   _Pragma("unroll")                                                            \
        for (int u = 0; u < 2; ++u) {                                                \
            _Pragma("unroll")                                                        \
            for (int v = 0; v < 4; ++v)                                              \
                acc[u][v] = __builtin_amdgcn_mfma_f32_16x16x32_f16(AF[u], BF[v], acc[u][v], 0, 0, 0); \
            float s_ = 0.f;                                                          \
            _Pragma("unroll")                                                        \
            for (int j = 0; j < 8; ++j) s_ += (float)AF[u][j];                       \
            dac[u] += s_;                                                            \
        }                                                                            \
    }
__launch_bounds__(256, 4)
__global__ void k2_spre(const f16* __restrict__ wT, const f16* __restrict__ yT,
                        float* __restrict__ spp, float* __restrict__ dpp) {
    const int tid = threadIdx.x, wave = tid >> 6, lane = tid & 63;
    const int quad = lane >> 4, col = lane & 15;
    const int slot = blockIdx.x >> 2, equad = blockIdx.x & 3;
    const int ebase = equad * 128 + wave * 32;

    const int ks0 = (slot * KSTEPS) >> 7;
    const int ks1 = ((slot + 1) * KSTEPS) >> 7;

    f32x4 acc[2][4];
    float dac[2];
    #pragma unroll
    for (int u = 0; u < 2; ++u) {
        dac[u] = 0.f;
        #pragma unroll
        for (int v = 0; v < 4; ++v) acc[u][v] = f32x4{0.f,0.f,0.f,0.f};
    }

    f16x8 afA[2], bfA[4], afB[2], bfB[4];
    K2_LOAD(afA, bfA, ks0)
    int ks = ks0;
    for (; ks + 2 <= ks1; ks += 2) {
        K2_LOAD(afB, bfB, ks + 1)
        K2_MFMA(afA, bfA)
        K2_LOAD(afA, bfA, ks + 2)   // one-step overread stays inside workspace; unused
        K2_MFMA(afB, bfB)
    }
    if (ks < ks1) K2_MFMA(afA, bfA)

    #pragma unroll
    for (int u = 0; u < 2; ++u) {
        dac[u] += __shfl_xor(dac[u], 16);
        dac[u] += __shfl_xor(dac[u], 32);
    }
    if (quad == 0) {
        #pragma unroll
        for (int u = 0; u < 2; ++u)
            dpp[slot*512 + ebase + u*16 + col] = dac[u];
    }
    float* dst = spp + (size_t)slot * 32768 + (size_t)equad * 8192;
    #pragma unroll
    for (int u = 0; u < 2; ++u)
        #pragma unroll
        for (int v = 0; v < 4; ++v)
            *(f32x4*)(dst + (size_t)((wave*2 + u)*4 + v)*256 + (size_t)lane*4) = acc[u][v];
}

// ---------------- K2r: reduce partials, de-swizzle frag order ----------------
__global__ void k2r_reduce(const float* __restrict__ spp, const float* __restrict__ dpp,
                           float* __restrict__ spre, float* __restrict__ dstd) {
    int i = blockIdx.x*256 + threadIdx.x;   // 32768
    float s = 0.f;
    for (int p = 0; p < K2SPL; ++p) s += spp[(size_t)p*32768 + i];
    int r = i & 3, L = (i >> 2) & 63, v = (i >> 8) & 3, g = (i >> 10) & 7, eq = (i >> 13) & 3;
    int e = eq*128 + (g >> 1)*32 + (g & 1)*16 + (L >> 4)*4 + r;
    int d = v*16 + (L & 15);
    spre[e*64 + d] = s;
    if (i < 512) {
        float tt = 0.f;
        for (int p = 0; p < K2SPL; ++p) tt += dpp[p*512 + i];
        dstd[i] = tt;
    }
}

// ---------------- K3: per-head middle block, m-split 4 ways (grid 32) ----------------
__global__ void k3_attn(const float* __restrict__ spre, const float* __restrict__ dstd,
                        const float* __restrict__ b1, const float* __restrict__ wq,
                        const float* __restrict__ wk, const float* __restrict__ wv,
                        const float* __restrict__ w3, const float* __restrict__ b3,
                        f16* __restrict__ sout) {
    __shared__ float wa[64][65], wb[64][65], wc[64][65];   // wq,wk,wv; wa reused for w3
    __shared__ float ss[64][65], kk[64][65], vv[64][65];
    __shared__ float qq[16][65], sc[16][65];               // slice-local
    const int h = blockIdx.x >> 2, ms = blockIdx.x & 3, tid = threadIdx.x;

    for (int i = tid; i < 4096; i += 256) {
        int r = i >> 6, c = i & 63;
        wa[r][c] = wq[i];
        wb[r][c] = wk[i];
        wc[r][c] = wv[i];
        ss[r][c] = spre[h*4096 + i] / (dstd[h*64 + r] + 1e-5f) + b1[c];
    }
    __syncthreads();

    #pragma unroll
    for (int it = 0; it < 16; ++it) {
        int m = it*4 + (tid >> 6), e = tid & 63;
        float ak = 0.f, av = 0.f;
        #pragma unroll 8
        for (int d = 0; d < 64; ++d) {
            float sv = ss[m][d];
            ak += sv * wb[e][d];
            av += sv * wc[e][d];
        }
        kk[m][e] = ak; vv[m][e] = av;
    }
    #pragma unroll
    for (int it = 0; it < 4; ++it) {
        int ml = it*4 + (tid >> 6), e = tid & 63;
        float aq = 0.f;
        #pragma unroll 8
        for (int d = 0; d < 64; ++d) aq += ss[ms*16 + ml][d] * wa[e][d];
        qq[ml][e] = aq;
    }
    __syncthreads();

    for (int i = tid; i < 4096; i += 256) wa[i >> 6][i & 63] = w3[i];
    #pragma unroll
    for (int it = 0; it < 4; ++it) {
        int ml = it*4 + (tid >> 6), l = tid & 63;
        float a = 0.f;
        #pragma unroll 8
        for (int e = 0; e < 64; ++e) a += qq[ml][e] * kk[l][e];
        sc[ml][l] = a * 0.125f;
    }
    __syncthreads();

    if (tid < 16) {
        int ml = tid;
        float mx = -1e30f;
        #pragma unroll 8
        for (int l = 0; l < 64; ++l) mx = fmaxf(mx, sc[ml][l]);
        float sm = 0.f;
        #pragma unroll 8
        for (int l = 0; l < 64; ++l) { float ev = __expf(sc[ml][l] - mx); sc[ml][l] = ev; sm += ev; }
        float rs = 1.0f / sm;
        #pragma unroll 8
        for (int l = 0; l < 64; ++l) sc[ml][l] *= rs;
    }
    __syncthreads();

    #pragma unroll
    for (int it = 0; it < 4; ++it) {
        int ml = it*4 + (tid >> 6), e = tid & 63;
        float a = 0.f;
        #pragma unroll 8
        for (int l = 0; l < 64; ++l) a += sc[ml][l] * vv[l][e];
        qq[ml][e] = a;
    }
    __syncthreads();

    #pragma unroll
    for (int it = 0; it < 4; ++it) {
        int d = it*16 + (tid >> 4), ml = tid & 15;
        float a = b3[d];
        #pragma unroll 8
        for (int e = 0; e < 64; ++e) a += qq[ml][e] * wa[d][e];
        sout[(h*64 + d)*64 + ms*16 + ml] = (f16)a;
    }
}

// ---------------- K4: deslice x_out = w @ s_out (wT gather, XCD-swizzled, coalesced stores) ----------------
#define K4PITCH 36                               // f16; 72 B rows, <=2-way LDS banks
__launch_bounds__(256, 4)
__global__ void k4_deslice(const f16* __restrict__ wT, const f16* __restrict__ sout,
                           float* __restrict__ out) {
    __shared__ __align__(16) char lmem[512 * K4PITCH * 2];   // 36864 B, aliased
    f16*   ldsW = (f16*)lmem;                    // [512][K4PITCH] gather stage
    float* ldsO = (float*)lmem;                  // [16][516] f32 store stage (33024 B)

    const int tid = threadIdx.x, wave = tid >> 6, lane = tid & 63;
    const int quad = lane >> 4, col = lane & 15;

    // bijective XCD swizzle (nwg = 3126 = 8*390 + 6): neighbors share wT lines
    const int bid = blockIdx.x;
    const int xcd = bid & 7, idx = bid >> 3;
    const int q = KSTEPS >> 3, r = KSTEPS & 7;   // 390, 6
    const int swz = (xcd < r ? xcd*(q+1) : r*(q+1) + (xcd - r)*q) + idx;
    const int n0 = swz * 32;

    // stage wT[:, n0:n0+32] -> ldsW[e][nlocal]
    #pragma unroll
    for (int i = 0; i < 8; ++i) {
        int id = tid + i*256;               // 2048 = 512 rows x 4 chunks(8 f16 = 16 B)
        int e = id >> 2, p = id & 3;
        f16x8 v = *(const f16x8*)(wT + (size_t)e*NPAD + n0 + p*8);
        *(f16x8*)(ldsW + (size_t)e*K4PITCH + p*8) = v;
    }
    __syncthreads();

    f32x4 acc[2][2][4];
    #pragma unroll
    for (int hh = 0; hh < 2; ++hh)
        #pragma unroll
        for (int t = 0; t < 2; ++t)
            #pragma unroll
            for (int v = 0; v < 4; ++v) acc[hh][t][v] = f32x4{0.f,0.f,0.f,0.f};

    #pragma unroll
    for (int hh = 0; hh < 2; ++hh) {
        int h = wave*2 + hh;
        #pragma unroll
        for (int ks = 0; ks < 2; ++ks) {
            f16x8 af[2], bf[4];
            #pragma unroll
            for (int t = 0; t < 2; ++t) {
                f16x8 a;
                #pragma unroll
                for (int j = 0; j < 8; ++j)
                    a[j] = ldsW[(size_t)(h*64 + ks*32 + quad*8 + j)*K4PITCH + t*16 + col];
                af[t] = a;
            }
            #pragma unroll
            for (int v = 0; v < 4; ++v)
                bf[v] = *(const f16x8*)(sout + (size_t)(h*64 + v*16 + col)*64 + ks*32 + quad*8);
            #pragma unroll
            for (int t = 0; t < 2; ++t)
                #pragma unroll
                for (int v = 0; v < 4; ++v)
                    acc[hh][t][v] = __builtin_amdgcn_mfma_f32_16x16x32_f16(af[t], bf[v], acc[hh][t][v], 0, 0, 0);
        }
    }

    // ---- epilogue: LDS transpose -> fully coalesced 2 KB-row stores (2 passes of 16 n) ----
    #pragma unroll
    for (int p = 0; p < 2; ++p) {
        __syncthreads();                         // p0: ldsW reads done; p1: p0 stores done
        #pragma unroll
        for (int hh = 0; hh < 2; ++hh) {
            int h = wave*2 + hh;
            #pragma unroll
            for (int v = 0; v < 4; ++v)
                #pragma unroll
                for (int r2 = 0; r2 < 4; ++r2)
                    ldsO[(size_t)(quad*4 + r2)*516 + h*64 + v*16 + col] = acc[hh][p][v][r2];
        }
        __syncthreads();
        #pragma unroll
        for (int it = 0; it < 8; ++it) {
            int id = tid + it*256;               // 2048 chunks of 16 B (16 rows x 128)
            int row = id >> 7, ch = id & 127;
            int n = n0 + p*16 + row;
            if (n < N_TOK) {
                float4 v4 = *(const float4*)(ldsO + (size_t)row*516 + ch*4);
                *(float4*)(out + (size_t)n*512 + ch*4) = v4;
            }
        }
    }
}

// ---------------- launcher ----------------
extern "C" void kernel_launch(void* const* d_in, const int* in_sizes, int n_in,
                              void* d_out, int out_size, void* d_ws, size_t ws_size,
                              hipStream_t stream) {
    const float* x           = (const float*)d_in[0];
    const float* temperature = (const float*)d_in[1];
    const float* w_slice     = (const float*)d_in[2];
    const float* b_slice     = (const float*)d_in[3];
    const float* w1          = (const float*)d_in[4];
    const float* b1          = (const float*)d_in[5];
    const float* wq          = (const float*)d_in[6];
    const float* wk          = (const float*)d_in[7];
    const float* wv          = (const float*)d_in[8];
    const float* w3          = (const float*)d_in[9];
    const float* b3          = (const float*)d_in[10];
    float* out = (float*)d_out;
    char*  ws  = (char*)d_ws;

    f16*   wT    = (f16*)(ws + O_WT);
    f16*   yT    = (f16*)(ws + O_YT);
    f16*   wfr   = (f16*)(ws + O_WFR);
    float* spp   = (float*)(ws + O_SPP);
    float* dpp   = (float*)(ws + O_DPP);
    float* spre  = (float*)(ws + O_SPRE);
    float* dstd  = (float*)(ws + O_DSTD);
    f16*   sout  = (f16*)(ws + O_SOUT);

    k0_pack<<<144, 256, 0, stream>>>(w_slice, w1, wfr);
    k1_slice<<<NT1*2, 256, 0, stream>>>(x, temperature, wfr, b_slice, wT, yT);
    k2_spre<<<K2SPL*4, 256, 0, stream>>>(wT, yT, spp, dpp);
    k2r_reduce<<<128, 256, 0, stream>>>(spp, dpp, spre, dstd);
    k3_attn<<<32, 256, 0, stream>>>(spre, dstd, b1, wq, wk, wv, w3, b3, sout);
    k4_deslice<<<KSTEPS, 256, 0, stream>>>(wT, sout, out);
}